// Round 8
// baseline (652.422 us; speedup 1.0000x reference)
//
#include <hip/hip_runtime.h>
#include <hip/hip_bf16.h>

// Problem constants (match reference)
#define N_NODES 50000
#define N_EDGES 800000
#define IN_C 256
#define HID_C 128
#define OUT_C 64

#define NB_SCAN ((N_NODES + 255) / 256)   // 196 blocks of 256 nodes
#define N_BINS ((N_NODES + 127) / 128)    // 391 dst-bins of 128 nodes

typedef __attribute__((ext_vector_type(8))) short bf16x8;
typedef __attribute__((ext_vector_type(4))) float f32x4;
typedef __attribute__((ext_vector_type(2))) _Float16 f16x2;

__device__ __forceinline__ ushort f2bf(float f) {
    uint u = __float_as_uint(f);
    u += 0x7fff + ((u >> 16) & 1);   // round-to-nearest-even
    return (ushort)(u >> 16);
}
__device__ __forceinline__ float bf2f(ushort h) {
    return __uint_as_float(((uint)h) << 16);
}

// ---------------------------------------------------------------------------
// Graph preprocessing
// ---------------------------------------------------------------------------

__global__ __launch_bounds__(256) void init_deg_kernel(int* __restrict__ degi,
                                                       int* __restrict__ bincur) {
    int i = blockIdx.x * 256 + threadIdx.x;
    if (i < N_NODES) degi[i] = 1;  // self-loop
    if (i < N_BINS) bincur[i] = 0;
}

__global__ __launch_bounds__(256) void count_deg_kernel(const int* __restrict__ dst,
                                                        int* __restrict__ degi) {
    int e = blockIdx.x * 256 + threadIdx.x;
    if (e < N_EDGES) atomicAdd(&degi[dst[e]], 1);
}

__global__ __launch_bounds__(256) void deg_partial_kernel(const int* __restrict__ degi,
                                                          int* __restrict__ partials) {
    __shared__ int s[256];
    int t = threadIdx.x;
    int i = blockIdx.x * 256 + t;
    s[t] = (i < N_NODES) ? degi[i] : 0;
    __syncthreads();
#pragma unroll
    for (int off = 128; off > 0; off >>= 1) {
        if (t < off) s[t] += s[t + off];
        __syncthreads();
    }
    if (t == 0) partials[blockIdx.x] = s[0];
}

__global__ __launch_bounds__(256) void scan_partials_kernel(const int* __restrict__ partials,
                                                            int* __restrict__ partial_off,
                                                            int* __restrict__ row_ptr) {
    __shared__ int s[256];
    int t = threadIdx.x;
    s[t] = (t < NB_SCAN) ? partials[t] : 0;
    __syncthreads();
#pragma unroll
    for (int off = 1; off < 256; off <<= 1) {
        int x = s[t];
        int add = (t >= off) ? s[t - off] : 0;
        __syncthreads();
        s[t] = x + add;
        __syncthreads();
    }
    if (t < NB_SCAN) partial_off[t] = (t == 0) ? 0 : s[t - 1];
    if (t == 255) row_ptr[N_NODES] = s[255];
}

__global__ __launch_bounds__(256) void scan_final_kernel(const int* __restrict__ degi,
                                                         const int* __restrict__ partial_off,
                                                         int* __restrict__ row_ptr,
                                                         int* __restrict__ cursor,
                                                         float* __restrict__ dis) {
    __shared__ int s[256];
    int t = threadIdx.x;
    int i = blockIdx.x * 256 + t;
    int d = (i < N_NODES) ? degi[i] : 0;
    s[t] = d;
    __syncthreads();
#pragma unroll
    for (int off = 1; off < 256; off <<= 1) {
        int x = s[t];
        int add = (t >= off) ? s[t - off] : 0;
        __syncthreads();
        s[t] = x + add;
        __syncthreads();
    }
    if (i < N_NODES) {
        int excl = partial_off[blockIdx.x] + s[t] - d;
        row_ptr[i] = excl;
        cursor[i] = excl;
        dis[i] = rsqrtf((float)d);
    }
}

// ---------------------------------------------------------------------------
// Two-pass binned CSR build. Edge packs into uint32 (src | dst<<16).
// Pass 1: scatter into 391 dst-bins; bin base = row_ptr[b*128] so the binned
// buffer is csr-aligned; write frontier = 391 hot lines (no amplification).
// Pass 2: stream bins sequentially; final csr slot lands in the bin's
// contiguous ~9 KB region (localized writes).
// ---------------------------------------------------------------------------

__global__ __launch_bounds__(256) void bin_scatter_kernel(const int* __restrict__ src,
                                                          const int* __restrict__ dst,
                                                          const int* __restrict__ row_ptr,
                                                          int* __restrict__ bincur,
                                                          uint* __restrict__ binned) {
    int i = blockIdx.x * 256 + threadIdx.x;
    if (i >= N_EDGES + N_NODES) return;
    int s, d;
    if (i < N_EDGES) {
        s = src[i];
        d = dst[i];
    } else {
        s = d = i - N_EDGES;
    }
    int b = d >> 7;
    int pos = row_ptr[b << 7] + atomicAdd(&bincur[b], 1);
    binned[pos] = (uint)s | ((uint)d << 16);
}

__global__ __launch_bounds__(256) void csr_scatter_kernel(const uint* __restrict__ binned,
                                                          int* __restrict__ cursor,
                                                          int* __restrict__ csr_src) {
    int i = blockIdx.x * 256 + threadIdx.x;
    if (i >= N_EDGES + N_NODES) return;
    uint e = binned[i];
    int s = (int)(e & 0xFFFFu);
    int d = (int)(e >> 16);
    int slot = atomicAdd(&cursor[d], 1);
    csr_src[slot] = s;
}

// ---------------------------------------------------------------------------
// Weight packing: W[K][N] fp32 -> fragment-ordered bf16 hi/lo
// layout: Pk[kt][ct][lane][j], element = W[kt*32 + (lane>>4)*8 + j][ct*16 + (lane&15)]
// ---------------------------------------------------------------------------

__global__ __launch_bounds__(64) void pack_w_kernel(const float* __restrict__ W,
                                                    ushort* __restrict__ Ph,
                                                    ushort* __restrict__ Pl,
                                                    int K, int N) {
    int lane = threadIdx.x;
    int CT = N / 16;
    int ct = blockIdx.x % CT;
    int kt = blockIdx.x / CT;
    int lr = lane & 15, lg = lane >> 4;
    size_t base = ((size_t)blockIdx.x * 64 + lane) * 8;
#pragma unroll
    for (int j = 0; j < 8; j++) {
        float w = W[(size_t)(kt * 32 + lg * 8 + j) * N + ct * 16 + lr];
        ushort h = f2bf(w);
        ushort lo = f2bf(w - bf2f(h));
        Ph[base + j] = h;
        Pl[base + j] = lo;
    }
}

// ---------------------------------------------------------------------------
// LDS-free MFMA GEMM with 3-term bf16 split.
// C[M][N] = A[M][K] @ W[K][N]. Wave owns 32 rows x N cols; block = 128 rows.
// OUT_MODE: 0 = fp32 + bias (row-major), 1 = bf16 hi/lo + bias (row-major),
//           2 = fp16 * dis[row] (row-major, no bias)
// ---------------------------------------------------------------------------

template <int K, int N, int OUT_MODE, bool AF32>
__global__ __launch_bounds__(256) void gemm_mfma_kernel(
    const float* __restrict__ Af, const ushort* __restrict__ Ahi,
    const ushort* __restrict__ Alo, const ushort* __restrict__ Wph,
    const ushort* __restrict__ Wpl, const float* __restrict__ bias,
    const float* __restrict__ disp, float* __restrict__ Cf,
    ushort* __restrict__ CHi, ushort* __restrict__ CLo, int M) {
    constexpr int CT = N / 16;
    constexpr int KT = K / 32;

    const int wid = threadIdx.x >> 6;
    const int lane = threadIdx.x & 63;
    const int lr = lane & 15;
    const int lg = lane >> 4;
    const int row_base = blockIdx.x * 128 + wid * 32;

    f32x4 acc[2][CT];
#pragma unroll
    for (int rt = 0; rt < 2; rt++)
#pragma unroll
        for (int ct = 0; ct < CT; ct++) acc[rt][ct] = (f32x4){0.f, 0.f, 0.f, 0.f};

    for (int kt = 0; kt < KT; kt++) {
        const int kof = kt * 32 + lg * 8;
        bf16x8 ah[2], al[2];
#pragma unroll
        for (int rt = 0; rt < 2; rt++) {
            int r = row_base + rt * 16 + lr;
            if (r >= M) r = M - 1;  // clamp; result discarded on store
            if (AF32) {
                const float* ap = &Af[(size_t)r * K + kof];
                float4 v0 = *(const float4*)ap;
                float4 v1 = *(const float4*)(ap + 4);
                float av[8] = {v0.x, v0.y, v0.z, v0.w, v1.x, v1.y, v1.z, v1.w};
#pragma unroll
                for (int j = 0; j < 8; j++) {
                    ushort h = f2bf(av[j]);
                    ushort lo = f2bf(av[j] - bf2f(h));
                    ah[rt][j] = (short)h;
                    al[rt][j] = (short)lo;
                }
            } else {
                ah[rt] = *(const bf16x8*)&Ahi[(size_t)r * K + kof];
                al[rt] = *(const bf16x8*)&Alo[(size_t)r * K + kof];
            }
        }
        const ushort* bh = &Wph[(size_t)kt * CT * 512 + (size_t)lane * 8];
        const ushort* bl = &Wpl[(size_t)kt * CT * 512 + (size_t)lane * 8];
#pragma unroll
        for (int ct = 0; ct < CT; ct++) {
            bf16x8 bhv = *(const bf16x8*)(bh + ct * 512);
            bf16x8 blv = *(const bf16x8*)(bl + ct * 512);
#pragma unroll
            for (int rt = 0; rt < 2; rt++) {
                acc[rt][ct] = __builtin_amdgcn_mfma_f32_16x16x32_bf16(ah[rt], bhv, acc[rt][ct], 0, 0, 0);
                acc[rt][ct] = __builtin_amdgcn_mfma_f32_16x16x32_bf16(al[rt], bhv, acc[rt][ct], 0, 0, 0);
                acc[rt][ct] = __builtin_amdgcn_mfma_f32_16x16x32_bf16(ah[rt], blv, acc[rt][ct], 0, 0, 0);
            }
        }
    }

    // Epilogue: D[row][col], row = rt*16 + lg*4 + j, col = ct*16 + lr
#pragma unroll
    for (int rt = 0; rt < 2; rt++)
#pragma unroll
        for (int ct = 0; ct < CT; ct++)
#pragma unroll
            for (int j = 0; j < 4; j++) {
                int r = row_base + rt * 16 + lg * 4 + j;
                if (r >= M) continue;
                int c = ct * 16 + lr;
                float v = acc[rt][ct][j];
                if (OUT_MODE == 2) {
                    // fp16 g, pre-scaled by dis[row]
                    _Float16* Ch = (_Float16*)Cf;
                    Ch[(size_t)r * N + c] = (_Float16)(v * disp[r]);
                } else {
                    v += bias[c];
                    if (OUT_MODE == 1) {
                        ushort h = f2bf(v);
                        ushort lo = f2bf(v - bf2f(h));
                        CHi[(size_t)r * N + c] = h;
                        CLo[(size_t)r * N + c] = lo;
                    } else {
                        Cf[(size_t)r * N + c] = v;
                    }
                }
            }
}

// ---------------------------------------------------------------------------
// CSR aggregation: wave = node, 64 lanes x half2 = full 128-ch fp16 row
// (256 B) per instruction. Edge loop unrolled x8 for MLP. g pre-scaled by
// dis[src] in the GEMM epilogue.
// out = relu(dis[node] * sum + bias) -> bf16 hi/lo (row-major).
// ---------------------------------------------------------------------------

__global__ __launch_bounds__(256) void aggregate_kernel(const _Float16* __restrict__ g,
                                                        const int* __restrict__ row_ptr,
                                                        const int* __restrict__ csr_src,
                                                        const float* __restrict__ dis,
                                                        const float* __restrict__ bias,
                                                        ushort* __restrict__ Hi,
                                                        ushort* __restrict__ Lo) {
    const int wid = threadIdx.x >> 6;
    const int lane = threadIdx.x & 63;
    const int node = blockIdx.x * 4 + wid;
    if (node >= N_NODES) return;
    const int c2 = lane * 2;

    const int s0 = row_ptr[node];
    const int s1 = row_ptr[node + 1];

    float ax = 0.f, ay = 0.f;
    int e = s0;
    for (; e + 8 <= s1; e += 8) {
        int i0 = csr_src[e + 0];
        int i1 = csr_src[e + 1];
        int i2 = csr_src[e + 2];
        int i3 = csr_src[e + 3];
        int i4 = csr_src[e + 4];
        int i5 = csr_src[e + 5];
        int i6 = csr_src[e + 6];
        int i7 = csr_src[e + 7];
        f16x2 v0 = *(const f16x2*)&g[(size_t)i0 * HID_C + c2];
        f16x2 v1 = *(const f16x2*)&g[(size_t)i1 * HID_C + c2];
        f16x2 v2 = *(const f16x2*)&g[(size_t)i2 * HID_C + c2];
        f16x2 v3 = *(const f16x2*)&g[(size_t)i3 * HID_C + c2];
        f16x2 v4 = *(const f16x2*)&g[(size_t)i4 * HID_C + c2];
        f16x2 v5 = *(const f16x2*)&g[(size_t)i5 * HID_C + c2];
        f16x2 v6 = *(const f16x2*)&g[(size_t)i6 * HID_C + c2];
        f16x2 v7 = *(const f16x2*)&g[(size_t)i7 * HID_C + c2];
        ax += (((float)v0.x + (float)v1.x) + ((float)v2.x + (float)v3.x)) +
              (((float)v4.x + (float)v5.x) + ((float)v6.x + (float)v7.x));
        ay += (((float)v0.y + (float)v1.y) + ((float)v2.y + (float)v3.y)) +
              (((float)v4.y + (float)v5.y) + ((float)v6.y + (float)v7.y));
    }
    for (; e < s1; e++) {
        int i0 = csr_src[e];
        f16x2 v0 = *(const f16x2*)&g[(size_t)i0 * HID_C + c2];
        ax += (float)v0.x;
        ay += (float)v0.y;
    }

    const float dn = dis[node];
    float2 bb = *(const float2*)&bias[c2];
    float vx = fmaxf(dn * ax + bb.x, 0.f);
    float vy = fmaxf(dn * ay + bb.y, 0.f);
    ushort hx = f2bf(vx), hy = f2bf(vy);
    ushort lx = f2bf(vx - bf2f(hx)), ly = f2bf(vy - bf2f(hy));
    uint hw = (uint)hx | ((uint)hy << 16);
    uint lw = (uint)lx | ((uint)ly << 16);
    *(uint*)&Hi[(size_t)node * HID_C + c2] = hw;
    *(uint*)&Lo[(size_t)node * HID_C + c2] = lw;
}

// ---------------------------------------------------------------------------
// Launch
// ---------------------------------------------------------------------------

extern "C" void kernel_launch(void* const* d_in, const int* in_sizes, int n_in,
                              void* d_out, int out_size, void* d_ws, size_t ws_size,
                              hipStream_t stream) {
    const float* x       = (const float*)d_in[0];
    const int*   eidx    = (const int*)d_in[1];
    const float* proj_W  = (const float*)d_in[2];
    const float* proj_b  = (const float*)d_in[3];
    const float* conv_W0 = (const float*)d_in[4];
    const float* conv_b0 = (const float*)d_in[5];
    const float* conv_W1 = (const float*)d_in[6];
    const float* conv_b1 = (const float*)d_in[7];
    const float* conv_W2 = (const float*)d_in[8];
    const float* conv_b2 = (const float*)d_in[9];
    const float* out_W   = (const float*)d_in[10];
    const float* out_b   = (const float*)d_in[11];
    float* out = (float*)d_out;

    const int* src = eidx;
    const int* dst = eidx + N_EDGES;

    char* ws = (char*)d_ws;
    size_t off = 0;
    auto carve = [&](size_t bytes) {
        void* p = ws + off;
        off += (bytes + 255) & ~(size_t)255;
        return p;
    };
    int*   degi     = (int*)carve(N_NODES * sizeof(int));
    int*   row_ptr  = (int*)carve((N_NODES + 1) * sizeof(int));
    int*   cursor   = (int*)carve(N_NODES * sizeof(int));
    int*   csr_src  = (int*)carve((size_t)(N_EDGES + N_NODES) * sizeof(int));
    uint*  binned   = (uint*)carve((size_t)(N_EDGES + N_NODES) * sizeof(uint));
    int*   bincur   = (int*)carve(N_BINS * sizeof(int));
    float* dis      = (float*)carve(N_NODES * sizeof(float));
    int*   partials = (int*)carve(NB_SCAN * sizeof(int));
    int*   poff     = (int*)carve(NB_SCAN * sizeof(int));
    ushort* projPh = (ushort*)carve((size_t)IN_C * HID_C * sizeof(ushort));
    ushort* projPl = (ushort*)carve((size_t)IN_C * HID_C * sizeof(ushort));
    ushort* convPh[3], *convPl[3];
    for (int l = 0; l < 3; l++) {
        convPh[l] = (ushort*)carve((size_t)HID_C * HID_C * sizeof(ushort));
        convPl[l] = (ushort*)carve((size_t)HID_C * HID_C * sizeof(ushort));
    }
    ushort* outPh = (ushort*)carve((size_t)HID_C * OUT_C * sizeof(ushort));
    ushort* outPl = (ushort*)carve((size_t)HID_C * OUT_C * sizeof(ushort));
    ushort* hHi = (ushort*)carve((size_t)N_NODES * HID_C * sizeof(ushort));
    ushort* hLo = (ushort*)carve((size_t)N_NODES * HID_C * sizeof(ushort));
    _Float16* g = (_Float16*)carve((size_t)N_NODES * HID_C * sizeof(_Float16));  // fp16 row-major

    // Graph preprocessing
    init_deg_kernel<<<NB_SCAN, 256, 0, stream>>>(degi, bincur);
    count_deg_kernel<<<(N_EDGES + 255) / 256, 256, 0, stream>>>(dst, degi);
    deg_partial_kernel<<<NB_SCAN, 256, 0, stream>>>(degi, partials);
    scan_partials_kernel<<<1, 256, 0, stream>>>(partials, poff, row_ptr);
    scan_final_kernel<<<NB_SCAN, 256, 0, stream>>>(degi, poff, row_ptr, cursor, dis);
    bin_scatter_kernel<<<(N_EDGES + N_NODES + 255) / 256, 256, 0, stream>>>(
        src, dst, row_ptr, bincur, binned);
    csr_scatter_kernel<<<(N_EDGES + N_NODES + 255) / 256, 256, 0, stream>>>(
        binned, cursor, csr_src);

    // Weight packing
    pack_w_kernel<<<(IN_C / 32) * (HID_C / 16), 64, 0, stream>>>(proj_W, projPh, projPl, IN_C, HID_C);
    pack_w_kernel<<<(HID_C / 32) * (HID_C / 16), 64, 0, stream>>>(conv_W0, convPh[0], convPl[0], HID_C, HID_C);
    pack_w_kernel<<<(HID_C / 32) * (HID_C / 16), 64, 0, stream>>>(conv_W1, convPh[1], convPl[1], HID_C, HID_C);
    pack_w_kernel<<<(HID_C / 32) * (HID_C / 16), 64, 0, stream>>>(conv_W2, convPh[2], convPl[2], HID_C, HID_C);
    pack_w_kernel<<<(HID_C / 32) * (OUT_C / 16), 64, 0, stream>>>(out_W, outPh, outPl, HID_C, OUT_C);

    const int gemm_grid = (N_NODES + 127) / 128;  // 391
    const int agg_grid = (N_NODES + 3) / 4;       // 12500

    // Projection: h = x @ proj_W + proj_b  -> hi/lo
    gemm_mfma_kernel<IN_C, HID_C, 1, true><<<gemm_grid, 256, 0, stream>>>(
        x, nullptr, nullptr, projPh, projPl, proj_b, nullptr, nullptr, hHi, hLo, N_NODES);

    // 3 GCN layers
    ushort* Wh_[3] = {convPh[0], convPh[1], convPh[2]};
    ushort* Wl_[3] = {convPl[0], convPl[1], convPl[2]};
    const float* bs_[3] = {conv_b0, conv_b1, conv_b2};
    for (int l = 0; l < 3; l++) {
        // g[node][128] = fp16(dis[node] * (h @ W)[node])
        gemm_mfma_kernel<HID_C, HID_C, 2, false><<<gemm_grid, 256, 0, stream>>>(
            nullptr, hHi, hLo, Wh_[l], Wl_[l], nullptr, dis, (float*)g, nullptr, nullptr, N_NODES);
        aggregate_kernel<<<agg_grid, 256, 0, stream>>>(
            g, row_ptr, csr_src, dis, bs_[l], hHi, hLo);
    }

    // Output: out = h @ out_W + out_b (fp32)
    gemm_mfma_kernel<HID_C, OUT_C, 0, false><<<gemm_grid, 256, 0, stream>>>(
        nullptr, hHi, hLo, outPh, outPl, out_b, nullptr, out, nullptr, nullptr, N_NODES);
}

// Round 9
// 340.222 us; speedup vs baseline: 1.9176x; 1.9176x over previous
//
#include <hip/hip_runtime.h>
#include <hip/hip_bf16.h>

// Problem constants (match reference)
#define N_NODES 50000
#define N_EDGES 800000
#define IN_C 256
#define HID_C 128
#define OUT_C 64

#define NB_SCAN ((N_NODES + 255) / 256)   // 196 blocks of 256 nodes
#define N_BINS ((N_NODES + 127) / 128)    // 391 dst-bins of 128 nodes

// Radix binning pass
#define RB_BLOCK 1024
#define RB_EPT 8
#define RB_CHUNK (RB_BLOCK * RB_EPT)      // 8192 edges per block
#define N_TOT (N_EDGES + N_NODES)         // 850000
#define RB_GRID ((N_TOT + RB_CHUNK - 1) / RB_CHUNK)  // 104

typedef __attribute__((ext_vector_type(8))) short bf16x8;
typedef __attribute__((ext_vector_type(4))) float f32x4;
typedef __attribute__((ext_vector_type(2))) _Float16 f16x2;

__device__ __forceinline__ ushort f2bf(float f) {
    uint u = __float_as_uint(f);
    u += 0x7fff + ((u >> 16) & 1);   // round-to-nearest-even
    return (ushort)(u >> 16);
}
__device__ __forceinline__ float bf2f(ushort h) {
    return __uint_as_float(((uint)h) << 16);
}

// ---------------------------------------------------------------------------
// Graph preprocessing
// ---------------------------------------------------------------------------

__global__ __launch_bounds__(256) void init_deg_kernel(int* __restrict__ degi,
                                                       int* __restrict__ bincur) {
    int i = blockIdx.x * 256 + threadIdx.x;
    if (i < N_NODES) degi[i] = 1;  // self-loop
    if (i < N_BINS) bincur[i] = 0;
}

__global__ __launch_bounds__(256) void count_deg_kernel(const int* __restrict__ dst,
                                                        int* __restrict__ degi) {
    int e = blockIdx.x * 256 + threadIdx.x;
    if (e < N_EDGES) atomicAdd(&degi[dst[e]], 1);
}

__global__ __launch_bounds__(256) void deg_partial_kernel(const int* __restrict__ degi,
                                                          int* __restrict__ partials) {
    __shared__ int s[256];
    int t = threadIdx.x;
    int i = blockIdx.x * 256 + t;
    s[t] = (i < N_NODES) ? degi[i] : 0;
    __syncthreads();
#pragma unroll
    for (int off = 128; off > 0; off >>= 1) {
        if (t < off) s[t] += s[t + off];
        __syncthreads();
    }
    if (t == 0) partials[blockIdx.x] = s[0];
}

__global__ __launch_bounds__(256) void scan_partials_kernel(const int* __restrict__ partials,
                                                            int* __restrict__ partial_off,
                                                            int* __restrict__ row_ptr) {
    __shared__ int s[256];
    int t = threadIdx.x;
    s[t] = (t < NB_SCAN) ? partials[t] : 0;
    __syncthreads();
#pragma unroll
    for (int off = 1; off < 256; off <<= 1) {
        int x = s[t];
        int add = (t >= off) ? s[t - off] : 0;
        __syncthreads();
        s[t] = x + add;
        __syncthreads();
    }
    if (t < NB_SCAN) partial_off[t] = (t == 0) ? 0 : s[t - 1];
    if (t == 255) row_ptr[N_NODES] = s[255];
}

__global__ __launch_bounds__(256) void scan_final_kernel(const int* __restrict__ degi,
                                                         const int* __restrict__ partial_off,
                                                         int* __restrict__ row_ptr,
                                                         int* __restrict__ cursor,
                                                         float* __restrict__ dis) {
    __shared__ int s[256];
    int t = threadIdx.x;
    int i = blockIdx.x * 256 + t;
    int d = (i < N_NODES) ? degi[i] : 0;
    s[t] = d;
    __syncthreads();
#pragma unroll
    for (int off = 1; off < 256; off <<= 1) {
        int x = s[t];
        int add = (t >= off) ? s[t - off] : 0;
        __syncthreads();
        s[t] = x + add;
        __syncthreads();
    }
    if (i < N_NODES) {
        int excl = partial_off[blockIdx.x] + s[t] - d;
        row_ptr[i] = excl;
        cursor[i] = excl;
        dis[i] = rsqrtf((float)d);
    }
}

// ---------------------------------------------------------------------------
// Two-pass binned CSR build, pass 1 = block-local LDS radix scatter.
// Each 1024-thr block takes 8192 edges: LDS histogram over 391 dst-bins,
// ONE global atomic per (block,bin) to reserve a range, then LDS-cursor
// scatter. Bin base = row_ptr[b*128] so binned is csr-region-aligned.
// ---------------------------------------------------------------------------

__global__ __launch_bounds__(RB_BLOCK) void bin_scatter_kernel(
    const int* __restrict__ src, const int* __restrict__ dst,
    const int* __restrict__ row_ptr, int* __restrict__ bincur,
    uint* __restrict__ binned) {
    __shared__ int hist[N_BINS];
    __shared__ int cur[N_BINS];
    const int t = threadIdx.x;
    for (int b = t; b < N_BINS; b += RB_BLOCK) hist[b] = 0;
    __syncthreads();

    uint pk[RB_EPT];
    int bn[RB_EPT];
    const int base = blockIdx.x * RB_CHUNK;
#pragma unroll
    for (int k = 0; k < RB_EPT; k++) {
        int i = base + k * RB_BLOCK + t;
        bn[k] = -1;
        if (i < N_TOT) {
            int s, d;
            if (i < N_EDGES) {
                s = src[i];
                d = dst[i];
            } else {
                s = d = i - N_EDGES;
            }
            pk[k] = (uint)s | ((uint)d << 16);
            bn[k] = d >> 7;
            atomicAdd(&hist[bn[k]], 1);
        }
    }
    __syncthreads();

    for (int b = t; b < N_BINS; b += RB_BLOCK) {
        int c = hist[b];
        int g0 = (c > 0) ? atomicAdd(&bincur[b], c) : 0;
        cur[b] = row_ptr[b << 7] + g0;
    }
    __syncthreads();

#pragma unroll
    for (int k = 0; k < RB_EPT; k++) {
        if (bn[k] >= 0) {
            int pos = atomicAdd(&cur[bn[k]], 1);
            binned[pos] = pk[k];
        }
    }
}

// Pass 2: stream bins sequentially; final csr slot lands in the bin's
// contiguous ~9 KB region (localized writes). csr_src is ushort (src<65536).
__global__ __launch_bounds__(256) void csr_scatter_kernel(const uint* __restrict__ binned,
                                                          int* __restrict__ cursor,
                                                          ushort* __restrict__ csr_src) {
    int i = blockIdx.x * 256 + threadIdx.x;
    if (i >= N_TOT) return;
    uint e = binned[i];
    int s = (int)(e & 0xFFFFu);
    int d = (int)(e >> 16);
    int slot = atomicAdd(&cursor[d], 1);
    csr_src[slot] = (ushort)s;
}

// ---------------------------------------------------------------------------
// Weight packing: W[K][N] fp32 -> fragment-ordered bf16 hi/lo
// layout: Pk[kt][ct][lane][j], element = W[kt*32 + (lane>>4)*8 + j][ct*16 + (lane&15)]
// ---------------------------------------------------------------------------

__global__ __launch_bounds__(64) void pack_w_kernel(const float* __restrict__ W,
                                                    ushort* __restrict__ Ph,
                                                    ushort* __restrict__ Pl,
                                                    int K, int N) {
    int lane = threadIdx.x;
    int CT = N / 16;
    int ct = blockIdx.x % CT;
    int kt = blockIdx.x / CT;
    int lr = lane & 15, lg = lane >> 4;
    size_t base = ((size_t)blockIdx.x * 64 + lane) * 8;
#pragma unroll
    for (int j = 0; j < 8; j++) {
        float w = W[(size_t)(kt * 32 + lg * 8 + j) * N + ct * 16 + lr];
        ushort h = f2bf(w);
        ushort lo = f2bf(w - bf2f(h));
        Ph[base + j] = h;
        Pl[base + j] = lo;
    }
}

// ---------------------------------------------------------------------------
// LDS-free MFMA GEMM with 3-term bf16 split.
// C[M][N] = A[M][K] @ W[K][N]. Wave owns 32 rows x N cols; block = 128 rows.
// OUT_MODE: 0 = fp32 + bias (row-major), 1 = bf16 hi/lo + bias (row-major),
//           2 = fp16 * dis[row] (row-major, no bias)
// ---------------------------------------------------------------------------

template <int K, int N, int OUT_MODE, bool AF32>
__global__ __launch_bounds__(256) void gemm_mfma_kernel(
    const float* __restrict__ Af, const ushort* __restrict__ Ahi,
    const ushort* __restrict__ Alo, const ushort* __restrict__ Wph,
    const ushort* __restrict__ Wpl, const float* __restrict__ bias,
    const float* __restrict__ disp, float* __restrict__ Cf,
    ushort* __restrict__ CHi, ushort* __restrict__ CLo, int M) {
    constexpr int CT = N / 16;
    constexpr int KT = K / 32;

    const int wid = threadIdx.x >> 6;
    const int lane = threadIdx.x & 63;
    const int lr = lane & 15;
    const int lg = lane >> 4;
    const int row_base = blockIdx.x * 128 + wid * 32;

    f32x4 acc[2][CT];
#pragma unroll
    for (int rt = 0; rt < 2; rt++)
#pragma unroll
        for (int ct = 0; ct < CT; ct++) acc[rt][ct] = (f32x4){0.f, 0.f, 0.f, 0.f};

    for (int kt = 0; kt < KT; kt++) {
        const int kof = kt * 32 + lg * 8;
        bf16x8 ah[2], al[2];
#pragma unroll
        for (int rt = 0; rt < 2; rt++) {
            int r = row_base + rt * 16 + lr;
            if (r >= M) r = M - 1;  // clamp; result discarded on store
            if (AF32) {
                const float* ap = &Af[(size_t)r * K + kof];
                float4 v0 = *(const float4*)ap;
                float4 v1 = *(const float4*)(ap + 4);
                float av[8] = {v0.x, v0.y, v0.z, v0.w, v1.x, v1.y, v1.z, v1.w};
#pragma unroll
                for (int j = 0; j < 8; j++) {
                    ushort h = f2bf(av[j]);
                    ushort lo = f2bf(av[j] - bf2f(h));
                    ah[rt][j] = (short)h;
                    al[rt][j] = (short)lo;
                }
            } else {
                ah[rt] = *(const bf16x8*)&Ahi[(size_t)r * K + kof];
                al[rt] = *(const bf16x8*)&Alo[(size_t)r * K + kof];
            }
        }
        const ushort* bh = &Wph[(size_t)kt * CT * 512 + (size_t)lane * 8];
        const ushort* bl = &Wpl[(size_t)kt * CT * 512 + (size_t)lane * 8];
#pragma unroll
        for (int ct = 0; ct < CT; ct++) {
            bf16x8 bhv = *(const bf16x8*)(bh + ct * 512);
            bf16x8 blv = *(const bf16x8*)(bl + ct * 512);
#pragma unroll
            for (int rt = 0; rt < 2; rt++) {
                acc[rt][ct] = __builtin_amdgcn_mfma_f32_16x16x32_bf16(ah[rt], bhv, acc[rt][ct], 0, 0, 0);
                acc[rt][ct] = __builtin_amdgcn_mfma_f32_16x16x32_bf16(al[rt], bhv, acc[rt][ct], 0, 0, 0);
                acc[rt][ct] = __builtin_amdgcn_mfma_f32_16x16x32_bf16(ah[rt], blv, acc[rt][ct], 0, 0, 0);
            }
        }
    }

    // Epilogue: D[row][col], row = rt*16 + lg*4 + j, col = ct*16 + lr
#pragma unroll
    for (int rt = 0; rt < 2; rt++)
#pragma unroll
        for (int ct = 0; ct < CT; ct++)
#pragma unroll
            for (int j = 0; j < 4; j++) {
                int r = row_base + rt * 16 + lg * 4 + j;
                if (r >= M) continue;
                int c = ct * 16 + lr;
                float v = acc[rt][ct][j];
                if (OUT_MODE == 2) {
                    // fp16 g, pre-scaled by dis[row]
                    _Float16* Ch = (_Float16*)Cf;
                    Ch[(size_t)r * N + c] = (_Float16)(v * disp[r]);
                } else {
                    v += bias[c];
                    if (OUT_MODE == 1) {
                        ushort h = f2bf(v);
                        ushort lo = f2bf(v - bf2f(h));
                        CHi[(size_t)r * N + c] = h;
                        CLo[(size_t)r * N + c] = lo;
                    } else {
                        Cf[(size_t)r * N + c] = v;
                    }
                }
            }
}

// ---------------------------------------------------------------------------
// CSR aggregation: wave = node, 64 lanes x half2 = full 128-ch fp16 row
// (256 B) per instruction. Edge loop unrolled x8 for MLP. g pre-scaled by
// dis[src] in the GEMM epilogue.
// out = relu(dis[node] * sum + bias) -> bf16 hi/lo (row-major).
// ---------------------------------------------------------------------------

__global__ __launch_bounds__(256) void aggregate_kernel(const _Float16* __restrict__ g,
                                                        const int* __restrict__ row_ptr,
                                                        const ushort* __restrict__ csr_src,
                                                        const float* __restrict__ dis,
                                                        const float* __restrict__ bias,
                                                        ushort* __restrict__ Hi,
                                                        ushort* __restrict__ Lo) {
    const int wid = threadIdx.x >> 6;
    const int lane = threadIdx.x & 63;
    const int node = blockIdx.x * 4 + wid;
    if (node >= N_NODES) return;
    const int c2 = lane * 2;

    const int s0 = row_ptr[node];
    const int s1 = row_ptr[node + 1];

    float ax = 0.f, ay = 0.f;
    int e = s0;
    for (; e + 8 <= s1; e += 8) {
        int i0 = csr_src[e + 0];
        int i1 = csr_src[e + 1];
        int i2 = csr_src[e + 2];
        int i3 = csr_src[e + 3];
        int i4 = csr_src[e + 4];
        int i5 = csr_src[e + 5];
        int i6 = csr_src[e + 6];
        int i7 = csr_src[e + 7];
        f16x2 v0 = *(const f16x2*)&g[(size_t)i0 * HID_C + c2];
        f16x2 v1 = *(const f16x2*)&g[(size_t)i1 * HID_C + c2];
        f16x2 v2 = *(const f16x2*)&g[(size_t)i2 * HID_C + c2];
        f16x2 v3 = *(const f16x2*)&g[(size_t)i3 * HID_C + c2];
        f16x2 v4 = *(const f16x2*)&g[(size_t)i4 * HID_C + c2];
        f16x2 v5 = *(const f16x2*)&g[(size_t)i5 * HID_C + c2];
        f16x2 v6 = *(const f16x2*)&g[(size_t)i6 * HID_C + c2];
        f16x2 v7 = *(const f16x2*)&g[(size_t)i7 * HID_C + c2];
        ax += (((float)v0.x + (float)v1.x) + ((float)v2.x + (float)v3.x)) +
              (((float)v4.x + (float)v5.x) + ((float)v6.x + (float)v7.x));
        ay += (((float)v0.y + (float)v1.y) + ((float)v2.y + (float)v3.y)) +
              (((float)v4.y + (float)v5.y) + ((float)v6.y + (float)v7.y));
    }
    for (; e < s1; e++) {
        int i0 = csr_src[e];
        f16x2 v0 = *(const f16x2*)&g[(size_t)i0 * HID_C + c2];
        ax += (float)v0.x;
        ay += (float)v0.y;
    }

    const float dn = dis[node];
    float2 bb = *(const float2*)&bias[c2];
    float vx = fmaxf(dn * ax + bb.x, 0.f);
    float vy = fmaxf(dn * ay + bb.y, 0.f);
    ushort hx = f2bf(vx), hy = f2bf(vy);
    ushort lx = f2bf(vx - bf2f(hx)), ly = f2bf(vy - bf2f(hy));
    uint hw = (uint)hx | ((uint)hy << 16);
    uint lw = (uint)lx | ((uint)ly << 16);
    *(uint*)&Hi[(size_t)node * HID_C + c2] = hw;
    *(uint*)&Lo[(size_t)node * HID_C + c2] = lw;
}

// ---------------------------------------------------------------------------
// Launch
// ---------------------------------------------------------------------------

extern "C" void kernel_launch(void* const* d_in, const int* in_sizes, int n_in,
                              void* d_out, int out_size, void* d_ws, size_t ws_size,
                              hipStream_t stream) {
    const float* x       = (const float*)d_in[0];
    const int*   eidx    = (const int*)d_in[1];
    const float* proj_W  = (const float*)d_in[2];
    const float* proj_b  = (const float*)d_in[3];
    const float* conv_W0 = (const float*)d_in[4];
    const float* conv_b0 = (const float*)d_in[5];
    const float* conv_W1 = (const float*)d_in[6];
    const float* conv_b1 = (const float*)d_in[7];
    const float* conv_W2 = (const float*)d_in[8];
    const float* conv_b2 = (const float*)d_in[9];
    const float* out_W   = (const float*)d_in[10];
    const float* out_b   = (const float*)d_in[11];
    float* out = (float*)d_out;

    const int* src = eidx;
    const int* dst = eidx + N_EDGES;

    char* ws = (char*)d_ws;
    size_t off = 0;
    auto carve = [&](size_t bytes) {
        void* p = ws + off;
        off += (bytes + 255) & ~(size_t)255;
        return p;
    };
    int*    degi     = (int*)carve(N_NODES * sizeof(int));
    int*    row_ptr  = (int*)carve((N_NODES + 1) * sizeof(int));
    int*    cursor   = (int*)carve(N_NODES * sizeof(int));
    ushort* csr_src  = (ushort*)carve((size_t)N_TOT * sizeof(ushort));
    uint*   binned   = (uint*)carve((size_t)N_TOT * sizeof(uint));
    int*    bincur   = (int*)carve(N_BINS * sizeof(int));
    float*  dis      = (float*)carve(N_NODES * sizeof(float));
    int*    partials = (int*)carve(NB_SCAN * sizeof(int));
    int*    poff     = (int*)carve(NB_SCAN * sizeof(int));
    ushort* projPh = (ushort*)carve((size_t)IN_C * HID_C * sizeof(ushort));
    ushort* projPl = (ushort*)carve((size_t)IN_C * HID_C * sizeof(ushort));
    ushort* convPh[3], *convPl[3];
    for (int l = 0; l < 3; l++) {
        convPh[l] = (ushort*)carve((size_t)HID_C * HID_C * sizeof(ushort));
        convPl[l] = (ushort*)carve((size_t)HID_C * HID_C * sizeof(ushort));
    }
    ushort* outPh = (ushort*)carve((size_t)HID_C * OUT_C * sizeof(ushort));
    ushort* outPl = (ushort*)carve((size_t)HID_C * OUT_C * sizeof(ushort));
    ushort* hHi = (ushort*)carve((size_t)N_NODES * HID_C * sizeof(ushort));
    ushort* hLo = (ushort*)carve((size_t)N_NODES * HID_C * sizeof(ushort));
    _Float16* g = (_Float16*)carve((size_t)N_NODES * HID_C * sizeof(_Float16));  // fp16 row-major

    // Graph preprocessing
    init_deg_kernel<<<NB_SCAN, 256, 0, stream>>>(degi, bincur);
    count_deg_kernel<<<(N_EDGES + 255) / 256, 256, 0, stream>>>(dst, degi);
    deg_partial_kernel<<<NB_SCAN, 256, 0, stream>>>(degi, partials);
    scan_partials_kernel<<<1, 256, 0, stream>>>(partials, poff, row_ptr);
    scan_final_kernel<<<NB_SCAN, 256, 0, stream>>>(degi, poff, row_ptr, cursor, dis);
    bin_scatter_kernel<<<RB_GRID, RB_BLOCK, 0, stream>>>(
        src, dst, row_ptr, bincur, binned);
    csr_scatter_kernel<<<(N_TOT + 255) / 256, 256, 0, stream>>>(
        binned, cursor, csr_src);

    // Weight packing
    pack_w_kernel<<<(IN_C / 32) * (HID_C / 16), 64, 0, stream>>>(proj_W, projPh, projPl, IN_C, HID_C);
    pack_w_kernel<<<(HID_C / 32) * (HID_C / 16), 64, 0, stream>>>(conv_W0, convPh[0], convPl[0], HID_C, HID_C);
    pack_w_kernel<<<(HID_C / 32) * (HID_C / 16), 64, 0, stream>>>(conv_W1, convPh[1], convPl[1], HID_C, HID_C);
    pack_w_kernel<<<(HID_C / 32) * (HID_C / 16), 64, 0, stream>>>(conv_W2, convPh[2], convPl[2], HID_C, HID_C);
    pack_w_kernel<<<(HID_C / 32) * (OUT_C / 16), 64, 0, stream>>>(out_W, outPh, outPl, HID_C, OUT_C);

    const int gemm_grid = (N_NODES + 127) / 128;  // 391
    const int agg_grid = (N_NODES + 3) / 4;       // 12500

    // Projection: h = x @ proj_W + proj_b  -> hi/lo
    gemm_mfma_kernel<IN_C, HID_C, 1, true><<<gemm_grid, 256, 0, stream>>>(
        x, nullptr, nullptr, projPh, projPl, proj_b, nullptr, nullptr, hHi, hLo, N_NODES);

    // 3 GCN layers
    ushort* Wh_[3] = {convPh[0], convPh[1], convPh[2]};
    ushort* Wl_[3] = {convPl[0], convPl[1], convPl[2]};
    const float* bs_[3] = {conv_b0, conv_b1, conv_b2};
    for (int l = 0; l < 3; l++) {
        // g[node][128] = fp16(dis[node] * (h @ W)[node])
        gemm_mfma_kernel<HID_C, HID_C, 2, false><<<gemm_grid, 256, 0, stream>>>(
            nullptr, hHi, hLo, Wh_[l], Wl_[l], nullptr, dis, (float*)g, nullptr, nullptr, N_NODES);
        aggregate_kernel<<<agg_grid, 256, 0, stream>>>(
            g, row_ptr, csr_src, dis, bs_[l], hHi, hLo);
    }

    // Output: out = h @ out_W + out_b (fp32)
    gemm_mfma_kernel<HID_C, OUT_C, 0, false><<<gemm_grid, 256, 0, stream>>>(
        nullptr, hHi, hLo, outPh, outPl, out_b, nullptr, out, nullptr, nullptr, N_NODES);
}

// Round 10
// 329.411 us; speedup vs baseline: 1.9806x; 1.0328x over previous
//
#include <hip/hip_runtime.h>
#include <hip/hip_bf16.h>

// Problem constants (match reference)
#define N_NODES 50000
#define N_EDGES 800000
#define IN_C 256
#define HID_C 128
#define OUT_C 64

#define NB_SCAN ((N_NODES + 255) / 256)   // 196 blocks of 256 nodes
#define N_BINS ((N_NODES + 127) / 128)    // 391 dst-bins of 128 nodes

// Radix binning pass
#define RB_BLOCK 1024
#define RB_EPT 8
#define RB_CHUNK (RB_BLOCK * RB_EPT)      // 8192 edges per block
#define N_TOT (N_EDGES + N_NODES)         // 850000
#define RB_GRID ((N_TOT + RB_CHUNK - 1) / RB_CHUNK)  // 104

typedef __attribute__((ext_vector_type(8))) short bf16x8;
typedef __attribute__((ext_vector_type(4))) float f32x4;
typedef __attribute__((ext_vector_type(2))) _Float16 f16x2;

__device__ __forceinline__ ushort f2bf(float f) {
    uint u = __float_as_uint(f);
    u += 0x7fff + ((u >> 16) & 1);   // round-to-nearest-even
    return (ushort)(u >> 16);
}
__device__ __forceinline__ float bf2f(ushort h) {
    return __uint_as_float(((uint)h) << 16);
}

// ---------------------------------------------------------------------------
// Graph preprocessing
// ---------------------------------------------------------------------------

__global__ __launch_bounds__(256) void init_deg_kernel(int* __restrict__ degi,
                                                       int* __restrict__ bincur) {
    int i = blockIdx.x * 256 + threadIdx.x;
    if (i < N_NODES) degi[i] = 1;  // self-loop
    if (i < N_BINS) bincur[i] = 0;
}

__global__ __launch_bounds__(256) void count_deg_kernel(const int* __restrict__ dst,
                                                        int* __restrict__ degi) {
    int e = blockIdx.x * 256 + threadIdx.x;
    if (e < N_EDGES) atomicAdd(&degi[dst[e]], 1);
}

__global__ __launch_bounds__(256) void deg_partial_kernel(const int* __restrict__ degi,
                                                          int* __restrict__ partials) {
    __shared__ int s[256];
    int t = threadIdx.x;
    int i = blockIdx.x * 256 + t;
    s[t] = (i < N_NODES) ? degi[i] : 0;
    __syncthreads();
#pragma unroll
    for (int off = 128; off > 0; off >>= 1) {
        if (t < off) s[t] += s[t + off];
        __syncthreads();
    }
    if (t == 0) partials[blockIdx.x] = s[0];
}

__global__ __launch_bounds__(256) void scan_partials_kernel(const int* __restrict__ partials,
                                                            int* __restrict__ partial_off,
                                                            int* __restrict__ row_ptr) {
    __shared__ int s[256];
    int t = threadIdx.x;
    s[t] = (t < NB_SCAN) ? partials[t] : 0;
    __syncthreads();
#pragma unroll
    for (int off = 1; off < 256; off <<= 1) {
        int x = s[t];
        int add = (t >= off) ? s[t - off] : 0;
        __syncthreads();
        s[t] = x + add;
        __syncthreads();
    }
    if (t < NB_SCAN) partial_off[t] = (t == 0) ? 0 : s[t - 1];
    if (t == 255) row_ptr[N_NODES] = s[255];
}

__global__ __launch_bounds__(256) void scan_final_kernel(const int* __restrict__ degi,
                                                         const int* __restrict__ partial_off,
                                                         int* __restrict__ row_ptr,
                                                         int* __restrict__ cursor,
                                                         float* __restrict__ dis) {
    __shared__ int s[256];
    int t = threadIdx.x;
    int i = blockIdx.x * 256 + t;
    int d = (i < N_NODES) ? degi[i] : 0;
    s[t] = d;
    __syncthreads();
#pragma unroll
    for (int off = 1; off < 256; off <<= 1) {
        int x = s[t];
        int add = (t >= off) ? s[t - off] : 0;
        __syncthreads();
        s[t] = x + add;
        __syncthreads();
    }
    if (i < N_NODES) {
        int excl = partial_off[blockIdx.x] + s[t] - d;
        row_ptr[i] = excl;
        cursor[i] = excl;
        dis[i] = rsqrtf((float)d);
    }
}

// ---------------------------------------------------------------------------
// Two-pass binned CSR build, pass 1 = block-local LDS radix scatter.
// ---------------------------------------------------------------------------

__global__ __launch_bounds__(RB_BLOCK) void bin_scatter_kernel(
    const int* __restrict__ src, const int* __restrict__ dst,
    const int* __restrict__ row_ptr, int* __restrict__ bincur,
    uint* __restrict__ binned) {
    __shared__ int hist[N_BINS];
    __shared__ int cur[N_BINS];
    const int t = threadIdx.x;
    for (int b = t; b < N_BINS; b += RB_BLOCK) hist[b] = 0;
    __syncthreads();

    uint pk[RB_EPT];
    int bn[RB_EPT];
    const int base = blockIdx.x * RB_CHUNK;
#pragma unroll
    for (int k = 0; k < RB_EPT; k++) {
        int i = base + k * RB_BLOCK + t;
        bn[k] = -1;
        if (i < N_TOT) {
            int s, d;
            if (i < N_EDGES) {
                s = src[i];
                d = dst[i];
            } else {
                s = d = i - N_EDGES;
            }
            pk[k] = (uint)s | ((uint)d << 16);
            bn[k] = d >> 7;
            atomicAdd(&hist[bn[k]], 1);
        }
    }
    __syncthreads();

    for (int b = t; b < N_BINS; b += RB_BLOCK) {
        int c = hist[b];
        int g0 = (c > 0) ? atomicAdd(&bincur[b], c) : 0;
        cur[b] = row_ptr[b << 7] + g0;
    }
    __syncthreads();

#pragma unroll
    for (int k = 0; k < RB_EPT; k++) {
        if (bn[k] >= 0) {
            int pos = atomicAdd(&cur[bn[k]], 1);
            binned[pos] = pk[k];
        }
    }
}

// Pass 2: stream bins sequentially; csr slot lands in the bin's contiguous
// ~9 KB region (localized writes). csr_src is ushort (src < 65536).
__global__ __launch_bounds__(256) void csr_scatter_kernel(const uint* __restrict__ binned,
                                                          int* __restrict__ cursor,
                                                          ushort* __restrict__ csr_src) {
    int i = blockIdx.x * 256 + threadIdx.x;
    if (i >= N_TOT) return;
    uint e = binned[i];
    int s = (int)(e & 0xFFFFu);
    int d = (int)(e >> 16);
    int slot = atomicAdd(&cursor[d], 1);
    csr_src[slot] = (ushort)s;
}

// ---------------------------------------------------------------------------
// Weight packing: W[K][N] fp32 -> fragment-ordered bf16 hi/lo
// layout: Pk[kt][ct][lane][j], element = W[kt*32 + (lane>>4)*8 + j][ct*16 + (lane&15)]
// ---------------------------------------------------------------------------

__global__ __launch_bounds__(64) void pack_w_kernel(const float* __restrict__ W,
                                                    ushort* __restrict__ Ph,
                                                    ushort* __restrict__ Pl,
                                                    int K, int N) {
    int lane = threadIdx.x;
    int CT = N / 16;
    int ct = blockIdx.x % CT;
    int kt = blockIdx.x / CT;
    int lr = lane & 15, lg = lane >> 4;
    size_t base = ((size_t)blockIdx.x * 64 + lane) * 8;
#pragma unroll
    for (int j = 0; j < 8; j++) {
        float w = W[(size_t)(kt * 32 + lg * 8 + j) * N + ct * 16 + lr];
        ushort h = f2bf(w);
        ushort lo = f2bf(w - bf2f(h));
        Ph[base + j] = h;
        Pl[base + j] = lo;
    }
}

// ---------------------------------------------------------------------------
// LDS-free MFMA GEMM, 3-term bf16 split, occupancy-optimized:
// wave = 16 rows x 64 cols (CT=4, acc=16 VGPR); block = 4 waves.
// N=128: block = 32 rows x 2 col-halves -> grid 1563 (~24 waves/CU).
// N=64:  block = 64 rows -> grid 782.
// A-fragments software-prefetched one kt ahead (hides global latency).
// OUT_MODE: 0 = fp32 + bias, 1 = bf16 hi/lo + bias, 2 = fp16 * dis[row]
// ---------------------------------------------------------------------------

template <int K, int N, int OUT_MODE, bool AF32>
__global__ __launch_bounds__(256) void gemm_mfma_kernel(
    const float* __restrict__ Af, const ushort* __restrict__ Ahi,
    const ushort* __restrict__ Alo, const ushort* __restrict__ Wph,
    const ushort* __restrict__ Wpl, const float* __restrict__ bias,
    const float* __restrict__ disp, float* __restrict__ Cf,
    ushort* __restrict__ CHi, ushort* __restrict__ CLo, int M) {
    constexpr int CT_TOT = N / 16;        // 8 (N=128) or 4 (N=64)
    constexpr int NWC = CT_TOT / 4;       // 2 or 1 col-halves
    constexpr int NWR = 4 / NWC;          // 2 or 4 row-groups
    constexpr int KT = K / 32;
    constexpr int RPB = NWR * 16;         // rows per block: 32 or 64

    const int wid = threadIdx.x >> 6;
    const int lane = threadIdx.x & 63;
    const int lr = lane & 15;
    const int lg = lane >> 4;
    const int wr = (NWC == 1) ? wid : (wid >> 1);
    const int wc = (NWC == 1) ? 0 : (wid & 1);
    const int row_base = blockIdx.x * RPB + wr * 16;
    const int ct0 = wc * 4;

    f32x4 acc[4];
#pragma unroll
    for (int ct = 0; ct < 4; ct++) acc[ct] = (f32x4){0.f, 0.f, 0.f, 0.f};

    int r = row_base + lr;
    if (r >= M) r = M - 1;  // clamp; result discarded on store
    const size_t arow = (size_t)r * K;

    // Prefetch registers (kt=0)
    bf16x8 ah, al;
    float4 v0, v1;
    if (AF32) {
        const float* ap = &Af[arow + lg * 8];
        v0 = *(const float4*)ap;
        v1 = *(const float4*)(ap + 4);
    } else {
        ah = *(const bf16x8*)&Ahi[arow + lg * 8];
        al = *(const bf16x8*)&Alo[arow + lg * 8];
    }

    for (int kt = 0; kt < KT; kt++) {
        // Capture current fragments, issue next-kt loads (latency hidden
        // behind this iteration's VALU + MFMA work)
        bf16x8 ahc, alc;
        if (AF32) {
            float4 v0c = v0, v1c = v1;
            if (kt + 1 < KT) {
                const float* ap = &Af[arow + (kt + 1) * 32 + lg * 8];
                v0 = *(const float4*)ap;
                v1 = *(const float4*)(ap + 4);
            }
            float av[8] = {v0c.x, v0c.y, v0c.z, v0c.w, v1c.x, v1c.y, v1c.z, v1c.w};
#pragma unroll
            for (int j = 0; j < 8; j++) {
                ushort h = f2bf(av[j]);
                ushort lo = f2bf(av[j] - bf2f(h));
                ahc[j] = (short)h;
                alc[j] = (short)lo;
            }
        } else {
            ahc = ah;
            alc = al;
            if (kt + 1 < KT) {
                ah = *(const bf16x8*)&Ahi[arow + (kt + 1) * 32 + lg * 8];
                al = *(const bf16x8*)&Alo[arow + (kt + 1) * 32 + lg * 8];
            }
        }

        // B fragments: 8 independent L2-resident loads, then 12 MFMAs
        const ushort* bh = &Wph[((size_t)kt * CT_TOT + ct0) * 512 + (size_t)lane * 8];
        const ushort* bl = &Wpl[((size_t)kt * CT_TOT + ct0) * 512 + (size_t)lane * 8];
        bf16x8 bhv[4], blv[4];
#pragma unroll
        for (int ct = 0; ct < 4; ct++) {
            bhv[ct] = *(const bf16x8*)(bh + ct * 512);
            blv[ct] = *(const bf16x8*)(bl + ct * 512);
        }
#pragma unroll
        for (int ct = 0; ct < 4; ct++) {
            acc[ct] = __builtin_amdgcn_mfma_f32_16x16x32_bf16(ahc, bhv[ct], acc[ct], 0, 0, 0);
            acc[ct] = __builtin_amdgcn_mfma_f32_16x16x32_bf16(alc, bhv[ct], acc[ct], 0, 0, 0);
            acc[ct] = __builtin_amdgcn_mfma_f32_16x16x32_bf16(ahc, blv[ct], acc[ct], 0, 0, 0);
        }
    }

    // Epilogue: D[row][col], row = lg*4 + j, col = (ct0+ct)*16 + lr
#pragma unroll
    for (int ct = 0; ct < 4; ct++)
#pragma unroll
        for (int j = 0; j < 4; j++) {
            int rr = row_base + lg * 4 + j;
            if (rr >= M) continue;
            int c = (ct0 + ct) * 16 + lr;
            float v = acc[ct][j];
            if (OUT_MODE == 2) {
                _Float16* Ch = (_Float16*)Cf;
                Ch[(size_t)rr * N + c] = (_Float16)(v * disp[rr]);
            } else {
                v += bias[c];
                if (OUT_MODE == 1) {
                    ushort h = f2bf(v);
                    ushort lo = f2bf(v - bf2f(h));
                    CHi[(size_t)rr * N + c] = h;
                    CLo[(size_t)rr * N + c] = lo;
                } else {
                    Cf[(size_t)rr * N + c] = v;
                }
            }
        }
}

// ---------------------------------------------------------------------------
// CSR aggregation: wave = node, 64 lanes x half2 = full 128-ch fp16 row
// (256 B) per instruction, unroll-8. g pre-scaled by dis[src] in GEMM.
// out = relu(dis[node] * sum + bias) -> bf16 hi/lo (row-major).
// ---------------------------------------------------------------------------

__global__ __launch_bounds__(256) void aggregate_kernel(const _Float16* __restrict__ g,
                                                        const int* __restrict__ row_ptr,
                                                        const ushort* __restrict__ csr_src,
                                                        const float* __restrict__ dis,
                                                        const float* __restrict__ bias,
                                                        ushort* __restrict__ Hi,
                                                        ushort* __restrict__ Lo) {
    const int wid = threadIdx.x >> 6;
    const int lane = threadIdx.x & 63;
    const int node = blockIdx.x * 4 + wid;
    if (node >= N_NODES) return;
    const int c2 = lane * 2;

    const int s0 = row_ptr[node];
    const int s1 = row_ptr[node + 1];

    float ax = 0.f, ay = 0.f;
    int e = s0;
    for (; e + 8 <= s1; e += 8) {
        int i0 = csr_src[e + 0];
        int i1 = csr_src[e + 1];
        int i2 = csr_src[e + 2];
        int i3 = csr_src[e + 3];
        int i4 = csr_src[e + 4];
        int i5 = csr_src[e + 5];
        int i6 = csr_src[e + 6];
        int i7 = csr_src[e + 7];
        f16x2 v0 = *(const f16x2*)&g[(size_t)i0 * HID_C + c2];
        f16x2 v1 = *(const f16x2*)&g[(size_t)i1 * HID_C + c2];
        f16x2 v2 = *(const f16x2*)&g[(size_t)i2 * HID_C + c2];
        f16x2 v3 = *(const f16x2*)&g[(size_t)i3 * HID_C + c2];
        f16x2 v4 = *(const f16x2*)&g[(size_t)i4 * HID_C + c2];
        f16x2 v5 = *(const f16x2*)&g[(size_t)i5 * HID_C + c2];
        f16x2 v6 = *(const f16x2*)&g[(size_t)i6 * HID_C + c2];
        f16x2 v7 = *(const f16x2*)&g[(size_t)i7 * HID_C + c2];
        ax += (((float)v0.x + (float)v1.x) + ((float)v2.x + (float)v3.x)) +
              (((float)v4.x + (float)v5.x) + ((float)v6.x + (float)v7.x));
        ay += (((float)v0.y + (float)v1.y) + ((float)v2.y + (float)v3.y)) +
              (((float)v4.y + (float)v5.y) + ((float)v6.y + (float)v7.y));
    }
    for (; e < s1; e++) {
        int i0 = csr_src[e];
        f16x2 v0 = *(const f16x2*)&g[(size_t)i0 * HID_C + c2];
        ax += (float)v0.x;
        ay += (float)v0.y;
    }

    const float dn = dis[node];
    float2 bb = *(const float2*)&bias[c2];
    float vx = fmaxf(dn * ax + bb.x, 0.f);
    float vy = fmaxf(dn * ay + bb.y, 0.f);
    ushort hx = f2bf(vx), hy = f2bf(vy);
    ushort lx = f2bf(vx - bf2f(hx)), ly = f2bf(vy - bf2f(hy));
    uint hw = (uint)hx | ((uint)hy << 16);
    uint lw = (uint)lx | ((uint)ly << 16);
    *(uint*)&Hi[(size_t)node * HID_C + c2] = hw;
    *(uint*)&Lo[(size_t)node * HID_C + c2] = lw;
}

// ---------------------------------------------------------------------------
// Launch
// ---------------------------------------------------------------------------

extern "C" void kernel_launch(void* const* d_in, const int* in_sizes, int n_in,
                              void* d_out, int out_size, void* d_ws, size_t ws_size,
                              hipStream_t stream) {
    const float* x       = (const float*)d_in[0];
    const int*   eidx    = (const int*)d_in[1];
    const float* proj_W  = (const float*)d_in[2];
    const float* proj_b  = (const float*)d_in[3];
    const float* conv_W0 = (const float*)d_in[4];
    const float* conv_b0 = (const float*)d_in[5];
    const float* conv_W1 = (const float*)d_in[6];
    const float* conv_b1 = (const float*)d_in[7];
    const float* conv_W2 = (const float*)d_in[8];
    const float* conv_b2 = (const float*)d_in[9];
    const float* out_W   = (const float*)d_in[10];
    const float* out_b   = (const float*)d_in[11];
    float* out = (float*)d_out;

    const int* src = eidx;
    const int* dst = eidx + N_EDGES;

    char* ws = (char*)d_ws;
    size_t off = 0;
    auto carve = [&](size_t bytes) {
        void* p = ws + off;
        off += (bytes + 255) & ~(size_t)255;
        return p;
    };
    int*    degi     = (int*)carve(N_NODES * sizeof(int));
    int*    row_ptr  = (int*)carve((N_NODES + 1) * sizeof(int));
    int*    cursor   = (int*)carve(N_NODES * sizeof(int));
    ushort* csr_src  = (ushort*)carve((size_t)N_TOT * sizeof(ushort));
    uint*   binned   = (uint*)carve((size_t)N_TOT * sizeof(uint));
    int*    bincur   = (int*)carve(N_BINS * sizeof(int));
    float*  dis      = (float*)carve(N_NODES * sizeof(float));
    int*    partials = (int*)carve(NB_SCAN * sizeof(int));
    int*    poff     = (int*)carve(NB_SCAN * sizeof(int));
    ushort* projPh = (ushort*)carve((size_t)IN_C * HID_C * sizeof(ushort));
    ushort* projPl = (ushort*)carve((size_t)IN_C * HID_C * sizeof(ushort));
    ushort* convPh[3], *convPl[3];
    for (int l = 0; l < 3; l++) {
        convPh[l] = (ushort*)carve((size_t)HID_C * HID_C * sizeof(ushort));
        convPl[l] = (ushort*)carve((size_t)HID_C * HID_C * sizeof(ushort));
    }
    ushort* outPh = (ushort*)carve((size_t)HID_C * OUT_C * sizeof(ushort));
    ushort* outPl = (ushort*)carve((size_t)HID_C * OUT_C * sizeof(ushort));
    ushort* hHi = (ushort*)carve((size_t)N_NODES * HID_C * sizeof(ushort));
    ushort* hLo = (ushort*)carve((size_t)N_NODES * HID_C * sizeof(ushort));
    _Float16* g = (_Float16*)carve((size_t)N_NODES * HID_C * sizeof(_Float16));  // fp16 row-major

    // Graph preprocessing
    init_deg_kernel<<<NB_SCAN, 256, 0, stream>>>(degi, bincur);
    count_deg_kernel<<<(N_EDGES + 255) / 256, 256, 0, stream>>>(dst, degi);
    deg_partial_kernel<<<NB_SCAN, 256, 0, stream>>>(degi, partials);
    scan_partials_kernel<<<1, 256, 0, stream>>>(partials, poff, row_ptr);
    scan_final_kernel<<<NB_SCAN, 256, 0, stream>>>(degi, poff, row_ptr, cursor, dis);
    bin_scatter_kernel<<<RB_GRID, RB_BLOCK, 0, stream>>>(
        src, dst, row_ptr, bincur, binned);
    csr_scatter_kernel<<<(N_TOT + 255) / 256, 256, 0, stream>>>(
        binned, cursor, csr_src);

    // Weight packing
    pack_w_kernel<<<(IN_C / 32) * (HID_C / 16), 64, 0, stream>>>(proj_W, projPh, projPl, IN_C, HID_C);
    pack_w_kernel<<<(HID_C / 32) * (HID_C / 16), 64, 0, stream>>>(conv_W0, convPh[0], convPl[0], HID_C, HID_C);
    pack_w_kernel<<<(HID_C / 32) * (HID_C / 16), 64, 0, stream>>>(conv_W1, convPh[1], convPl[1], HID_C, HID_C);
    pack_w_kernel<<<(HID_C / 32) * (HID_C / 16), 64, 0, stream>>>(conv_W2, convPh[2], convPl[2], HID_C, HID_C);
    pack_w_kernel<<<(HID_C / 32) * (OUT_C / 16), 64, 0, stream>>>(out_W, outPh, outPl, HID_C, OUT_C);

    const int grid_n128 = (N_NODES + 31) / 32;   // 1563 (N=128 kernels)
    const int grid_n64  = (N_NODES + 63) / 64;   // 782  (N=64 kernel)
    const int agg_grid  = (N_NODES + 3) / 4;     // 12500

    // Projection: h = x @ proj_W + proj_b  -> hi/lo
    gemm_mfma_kernel<IN_C, HID_C, 1, true><<<grid_n128, 256, 0, stream>>>(
        x, nullptr, nullptr, projPh, projPl, proj_b, nullptr, nullptr, hHi, hLo, N_NODES);

    // 3 GCN layers
    ushort* Wh_[3] = {convPh[0], convPh[1], convPh[2]};
    ushort* Wl_[3] = {convPl[0], convPl[1], convPl[2]};
    const float* bs_[3] = {conv_b0, conv_b1, conv_b2};
    for (int l = 0; l < 3; l++) {
        // g[node][128] = fp16(dis[node] * (h @ W)[node])
        gemm_mfma_kernel<HID_C, HID_C, 2, false><<<grid_n128, 256, 0, stream>>>(
            nullptr, hHi, hLo, Wh_[l], Wl_[l], nullptr, dis, (float*)g, nullptr, nullptr, N_NODES);
        aggregate_kernel<<<agg_grid, 256, 0, stream>>>(
            g, row_ptr, csr_src, dis, bs_[l], hHi, hLo);
    }

    // Output: out = h @ out_W + out_b (fp32)
    gemm_mfma_kernel<HID_C, OUT_C, 0, false><<<grid_n64, 256, 0, stream>>>(
        nullptr, hHi, hLo, outPh, outPl, out_b, nullptr, out, nullptr, nullptr, N_NODES);
}

// Round 11
// 323.684 us; speedup vs baseline: 2.0156x; 1.0177x over previous
//
#include <hip/hip_runtime.h>
#include <hip/hip_bf16.h>

// Problem constants (match reference)
#define N_NODES 50000
#define N_EDGES 800000
#define IN_C 256
#define HID_C 128
#define OUT_C 64

#define NB_SCAN ((N_NODES + 255) / 256)   // 196 blocks of 256 nodes
#define N_BINS ((N_NODES + 127) / 128)    // 391 dst-bins of 128 nodes

// Radix binning pass
#define RB_BLOCK 1024
#define RB_EPT 8
#define RB_CHUNK (RB_BLOCK * RB_EPT)      // 8192 edges per block
#define N_TOT (N_EDGES + N_NODES)         // 850000
#define RB_GRID ((N_TOT + RB_CHUNK - 1) / RB_CHUNK)  // 104

typedef __attribute__((ext_vector_type(8))) short bf16x8;
typedef __attribute__((ext_vector_type(4))) float f32x4;
typedef __attribute__((ext_vector_type(2))) _Float16 f16x2;

__device__ __forceinline__ ushort f2bf(float f) {
    uint u = __float_as_uint(f);
    u += 0x7fff + ((u >> 16) & 1);   // round-to-nearest-even
    return (ushort)(u >> 16);
}
__device__ __forceinline__ float bf2f(ushort h) {
    return __uint_as_float(((uint)h) << 16);
}
// Pack one fp32 value into uint: bf16(hi)<<16 | bf16(residual lo)
__device__ __forceinline__ uint packhl(float v) {
    ushort h = f2bf(v);
    ushort l = f2bf(v - bf2f(h));
    return ((uint)h << 16) | (uint)l;
}

// ---------------------------------------------------------------------------
// Graph preprocessing
// ---------------------------------------------------------------------------

__global__ __launch_bounds__(256) void init_deg_kernel(int* __restrict__ degi,
                                                       int* __restrict__ bincur) {
    int i = blockIdx.x * 256 + threadIdx.x;
    if (i < N_NODES) degi[i] = 1;  // self-loop
    if (i < N_BINS) bincur[i] = 0;
}

__global__ __launch_bounds__(256) void count_deg_kernel(const int* __restrict__ dst,
                                                        int* __restrict__ degi) {
    int e = blockIdx.x * 256 + threadIdx.x;
    if (e < N_EDGES) atomicAdd(&degi[dst[e]], 1);
}

__global__ __launch_bounds__(256) void deg_partial_kernel(const int* __restrict__ degi,
                                                          int* __restrict__ partials) {
    __shared__ int s[256];
    int t = threadIdx.x;
    int i = blockIdx.x * 256 + t;
    s[t] = (i < N_NODES) ? degi[i] : 0;
    __syncthreads();
#pragma unroll
    for (int off = 128; off > 0; off >>= 1) {
        if (t < off) s[t] += s[t + off];
        __syncthreads();
    }
    if (t == 0) partials[blockIdx.x] = s[0];
}

__global__ __launch_bounds__(256) void scan_partials_kernel(const int* __restrict__ partials,
                                                            int* __restrict__ partial_off,
                                                            int* __restrict__ row_ptr) {
    __shared__ int s[256];
    int t = threadIdx.x;
    s[t] = (t < NB_SCAN) ? partials[t] : 0;
    __syncthreads();
#pragma unroll
    for (int off = 1; off < 256; off <<= 1) {
        int x = s[t];
        int add = (t >= off) ? s[t - off] : 0;
        __syncthreads();
        s[t] = x + add;
        __syncthreads();
    }
    if (t < NB_SCAN) partial_off[t] = (t == 0) ? 0 : s[t - 1];
    if (t == 255) row_ptr[N_NODES] = s[255];
}

__global__ __launch_bounds__(256) void scan_final_kernel(const int* __restrict__ degi,
                                                         const int* __restrict__ partial_off,
                                                         int* __restrict__ row_ptr,
                                                         int* __restrict__ cursor,
                                                         float* __restrict__ dis) {
    __shared__ int s[256];
    int t = threadIdx.x;
    int i = blockIdx.x * 256 + t;
    int d = (i < N_NODES) ? degi[i] : 0;
    s[t] = d;
    __syncthreads();
#pragma unroll
    for (int off = 1; off < 256; off <<= 1) {
        int x = s[t];
        int add = (t >= off) ? s[t - off] : 0;
        __syncthreads();
        s[t] = x + add;
        __syncthreads();
    }
    if (i < N_NODES) {
        int excl = partial_off[blockIdx.x] + s[t] - d;
        row_ptr[i] = excl;
        cursor[i] = excl;
        dis[i] = rsqrtf((float)d);
    }
}

// ---------------------------------------------------------------------------
// Two-pass binned CSR build, pass 1 = block-local LDS radix scatter.
// ---------------------------------------------------------------------------

__global__ __launch_bounds__(RB_BLOCK) void bin_scatter_kernel(
    const int* __restrict__ src, const int* __restrict__ dst,
    const int* __restrict__ row_ptr, int* __restrict__ bincur,
    uint* __restrict__ binned) {
    __shared__ int hist[N_BINS];
    __shared__ int cur[N_BINS];
    const int t = threadIdx.x;
    for (int b = t; b < N_BINS; b += RB_BLOCK) hist[b] = 0;
    __syncthreads();

    uint pk[RB_EPT];
    int bn[RB_EPT];
    const int base = blockIdx.x * RB_CHUNK;
#pragma unroll
    for (int k = 0; k < RB_EPT; k++) {
        int i = base + k * RB_BLOCK + t;
        bn[k] = -1;
        if (i < N_TOT) {
            int s, d;
            if (i < N_EDGES) {
                s = src[i];
                d = dst[i];
            } else {
                s = d = i - N_EDGES;
            }
            pk[k] = (uint)s | ((uint)d << 16);
            bn[k] = d >> 7;
            atomicAdd(&hist[bn[k]], 1);
        }
    }
    __syncthreads();

    for (int b = t; b < N_BINS; b += RB_BLOCK) {
        int c = hist[b];
        int g0 = (c > 0) ? atomicAdd(&bincur[b], c) : 0;
        cur[b] = row_ptr[b << 7] + g0;
    }
    __syncthreads();

#pragma unroll
    for (int k = 0; k < RB_EPT; k++) {
        if (bn[k] >= 0) {
            int pos = atomicAdd(&cur[bn[k]], 1);
            binned[pos] = pk[k];
        }
    }
}

// Pass 2: stream bins sequentially; csr slot lands in the bin's contiguous
// ~9 KB region (localized writes). csr_src is ushort (src < 65536).
__global__ __launch_bounds__(256) void csr_scatter_kernel(const uint* __restrict__ binned,
                                                          int* __restrict__ cursor,
                                                          ushort* __restrict__ csr_src) {
    int i = blockIdx.x * 256 + threadIdx.x;
    if (i >= N_TOT) return;
    uint e = binned[i];
    int s = (int)(e & 0xFFFFu);
    int d = (int)(e >> 16);
    int slot = atomicAdd(&cursor[d], 1);
    csr_src[slot] = (ushort)s;
}

// ---------------------------------------------------------------------------
// Weight packing: W[K][N] fp32 -> fragment-ordered bf16 hi/lo
// layout: Pk[kt][ct][lane][j], element = W[kt*32 + (lane>>4)*8 + j][ct*16 + (lane&15)]
// ---------------------------------------------------------------------------

__global__ __launch_bounds__(64) void pack_w_kernel(const float* __restrict__ W,
                                                    ushort* __restrict__ Ph,
                                                    ushort* __restrict__ Pl,
                                                    int K, int N) {
    int lane = threadIdx.x;
    int CT = N / 16;
    int ct = blockIdx.x % CT;
    int kt = blockIdx.x / CT;
    int lr = lane & 15, lg = lane >> 4;
    size_t base = ((size_t)blockIdx.x * 64 + lane) * 8;
#pragma unroll
    for (int j = 0; j < 8; j++) {
        float w = W[(size_t)(kt * 32 + lg * 8 + j) * N + ct * 16 + lr];
        ushort h = f2bf(w);
        ushort lo = f2bf(w - bf2f(h));
        Ph[base + j] = h;
        Pl[base + j] = lo;
    }
}

// ---------------------------------------------------------------------------
// LDS-free MFMA GEMM, 3-term bf16 split, packed activations.
// wave = 16 rows x 64 cols (CT=4, acc=16 VGPR); block = 4 waves.
// A source: AF32 -> fp32 (proj, depth-2 pipelined, B issued before A-next);
//           else packed uint hx (hi<<16|lo), ALL A loads hoisted to prologue.
// OUT_MODE: 0 = fp32 + bias, 1 = packed uint + bias, 2 = fp16 * dis[row]
// ---------------------------------------------------------------------------

template <int K, int N, int OUT_MODE, bool AF32>
__global__ __launch_bounds__(256) void gemm_mfma_kernel(
    const float* __restrict__ Af, const uint* __restrict__ Ax,
    const ushort* __restrict__ Wph, const ushort* __restrict__ Wpl,
    const float* __restrict__ bias, const float* __restrict__ disp,
    float* __restrict__ Cf, uint* __restrict__ Cx, _Float16* __restrict__ Ch,
    int M) {
    constexpr int CT_TOT = N / 16;        // 8 (N=128) or 4 (N=64)
    constexpr int NWC = CT_TOT / 4;       // 2 or 1 col-halves
    constexpr int NWR = 4 / NWC;          // 2 or 4 row-groups
    constexpr int KT = K / 32;
    constexpr int RPB = NWR * 16;         // rows per block: 32 or 64

    const int wid = threadIdx.x >> 6;
    const int lane = threadIdx.x & 63;
    const int lr = lane & 15;
    const int lg = lane >> 4;
    const int wr = (NWC == 1) ? wid : (wid >> 1);
    const int wc = (NWC == 1) ? 0 : (wid & 1);
    const int row_base = blockIdx.x * RPB + wr * 16;
    const int ct0 = wc * 4;

    f32x4 acc[4];
#pragma unroll
    for (int ct = 0; ct < 4; ct++) acc[ct] = (f32x4){0.f, 0.f, 0.f, 0.f};

    int r = row_base + lr;
    if (r >= M) r = M - 1;  // clamp; result discarded on store

    // ---- A staging ----
    uint4 apk[AF32 ? 1 : KT][2];          // packed path: all kt hoisted
    float4 v0a, v1a;                      // fp32 path: depth-2 rotation
    if (AF32) {
        const float* ap = &Af[(size_t)r * K + lg * 8];
        v0a = *(const float4*)ap;
        v1a = *(const float4*)(ap + 4);
    } else {
        const uint* ab = &Ax[(size_t)r * K + lg * 8];
#pragma unroll
        for (int kt = 0; kt < KT; kt++) {
            apk[kt][0] = *(const uint4*)(ab + kt * 32);
            apk[kt][1] = *(const uint4*)(ab + kt * 32 + 4);
        }
    }

#pragma unroll
    for (int kt = 0; kt < KT; kt++) {
        // B fragments first (oldest in VMEM FIFO -> MFMA wait leaves A-next in flight)
        const ushort* bh = &Wph[((size_t)kt * CT_TOT + ct0) * 512 + (size_t)lane * 8];
        const ushort* bl = &Wpl[((size_t)kt * CT_TOT + ct0) * 512 + (size_t)lane * 8];
        bf16x8 bhv[4], blv[4];
#pragma unroll
        for (int ct = 0; ct < 4; ct++) {
            bhv[ct] = *(const bf16x8*)(bh + ct * 512);
            blv[ct] = *(const bf16x8*)(bl + ct * 512);
        }

        // Build current A fragments
        bf16x8 ah, al;
        if (AF32) {
            float4 v0c = v0a, v1c = v1a;
            if (kt + 1 < KT) {  // issue next-kt A AFTER this kt's B loads
                const float* ap = &Af[(size_t)r * K + (kt + 1) * 32 + lg * 8];
                v0a = *(const float4*)ap;
                v1a = *(const float4*)(ap + 4);
            }
            float av[8] = {v0c.x, v0c.y, v0c.z, v0c.w, v1c.x, v1c.y, v1c.z, v1c.w};
#pragma unroll
            for (int j = 0; j < 8; j++) {
                ushort h = f2bf(av[j]);
                ushort lo = f2bf(av[j] - bf2f(h));
                ah[j] = (short)h;
                al[j] = (short)lo;
            }
        } else {
            union { uint u[4]; bf16x8 v; } ch_, cl_;
#pragma unroll
            for (int j = 0; j < 4; j++) {
                uint u0 = (j < 2) ? ((const uint*)&apk[kt][0])[j * 2]
                                  : ((const uint*)&apk[kt][1])[(j - 2) * 2];
                uint u1 = (j < 2) ? ((const uint*)&apk[kt][0])[j * 2 + 1]
                                  : ((const uint*)&apk[kt][1])[(j - 2) * 2 + 1];
                ch_.u[j] = (u0 >> 16) | (u1 & 0xFFFF0000u);
                cl_.u[j] = (u0 & 0xFFFFu) | (u1 << 16);
            }
            ah = ch_.v;
            al = cl_.v;
        }

#pragma unroll
        for (int ct = 0; ct < 4; ct++) {
            acc[ct] = __builtin_amdgcn_mfma_f32_16x16x32_bf16(ah, bhv[ct], acc[ct], 0, 0, 0);
            acc[ct] = __builtin_amdgcn_mfma_f32_16x16x32_bf16(al, bhv[ct], acc[ct], 0, 0, 0);
            acc[ct] = __builtin_amdgcn_mfma_f32_16x16x32_bf16(ah, blv[ct], acc[ct], 0, 0, 0);
        }
    }

    // Epilogue: D[row][col], row = lg*4 + j, col = (ct0+ct)*16 + lr
#pragma unroll
    for (int ct = 0; ct < 4; ct++)
#pragma unroll
        for (int j = 0; j < 4; j++) {
            int rr = row_base + lg * 4 + j;
            if (rr >= M) continue;
            int c = (ct0 + ct) * 16 + lr;
            float v = acc[ct][j];
            if (OUT_MODE == 2) {
                Ch[(size_t)rr * N + c] = (_Float16)(v * disp[rr]);
            } else if (OUT_MODE == 1) {
                Cx[(size_t)rr * N + c] = packhl(v + bias[c]);
            } else {
                Cf[(size_t)rr * N + c] = v + bias[c];
            }
        }
}

// ---------------------------------------------------------------------------
// CSR aggregation: wave = node, 64 lanes x half2 = full 128-ch fp16 row
// (256 B) per instruction, unroll-8. g pre-scaled by dis[src] in GEMM.
// out = relu(dis[node] * sum + bias) -> packed uint (one uint2/lane, 512 B
// contiguous per wave).
// ---------------------------------------------------------------------------

__global__ __launch_bounds__(256) void aggregate_kernel(const _Float16* __restrict__ g,
                                                        const int* __restrict__ row_ptr,
                                                        const ushort* __restrict__ csr_src,
                                                        const float* __restrict__ dis,
                                                        const float* __restrict__ bias,
                                                        uint* __restrict__ hx) {
    const int wid = threadIdx.x >> 6;
    const int lane = threadIdx.x & 63;
    const int node = blockIdx.x * 4 + wid;
    if (node >= N_NODES) return;
    const int c2 = lane * 2;

    const int s0 = row_ptr[node];
    const int s1 = row_ptr[node + 1];

    float ax = 0.f, ay = 0.f;
    int e = s0;
    for (; e + 8 <= s1; e += 8) {
        int i0 = csr_src[e + 0];
        int i1 = csr_src[e + 1];
        int i2 = csr_src[e + 2];
        int i3 = csr_src[e + 3];
        int i4 = csr_src[e + 4];
        int i5 = csr_src[e + 5];
        int i6 = csr_src[e + 6];
        int i7 = csr_src[e + 7];
        f16x2 v0 = *(const f16x2*)&g[(size_t)i0 * HID_C + c2];
        f16x2 v1 = *(const f16x2*)&g[(size_t)i1 * HID_C + c2];
        f16x2 v2 = *(const f16x2*)&g[(size_t)i2 * HID_C + c2];
        f16x2 v3 = *(const f16x2*)&g[(size_t)i3 * HID_C + c2];
        f16x2 v4 = *(const f16x2*)&g[(size_t)i4 * HID_C + c2];
        f16x2 v5 = *(const f16x2*)&g[(size_t)i5 * HID_C + c2];
        f16x2 v6 = *(const f16x2*)&g[(size_t)i6 * HID_C + c2];
        f16x2 v7 = *(const f16x2*)&g[(size_t)i7 * HID_C + c2];
        ax += (((float)v0.x + (float)v1.x) + ((float)v2.x + (float)v3.x)) +
              (((float)v4.x + (float)v5.x) + ((float)v6.x + (float)v7.x));
        ay += (((float)v0.y + (float)v1.y) + ((float)v2.y + (float)v3.y)) +
              (((float)v4.y + (float)v5.y) + ((float)v6.y + (float)v7.y));
    }
    for (; e < s1; e++) {
        int i0 = csr_src[e];
        f16x2 v0 = *(const f16x2*)&g[(size_t)i0 * HID_C + c2];
        ax += (float)v0.x;
        ay += (float)v0.y;
    }

    const float dn = dis[node];
    float2 bb = *(const float2*)&bias[c2];
    float vx = fmaxf(dn * ax + bb.x, 0.f);
    float vy = fmaxf(dn * ay + bb.y, 0.f);
    uint2 w;
    w.x = packhl(vx);
    w.y = packhl(vy);
    *(uint2*)&hx[(size_t)node * HID_C + c2] = w;
}

// ---------------------------------------------------------------------------
// Launch
// ---------------------------------------------------------------------------

extern "C" void kernel_launch(void* const* d_in, const int* in_sizes, int n_in,
                              void* d_out, int out_size, void* d_ws, size_t ws_size,
                              hipStream_t stream) {
    const float* x       = (const float*)d_in[0];
    const int*   eidx    = (const int*)d_in[1];
    const float* proj_W  = (const float*)d_in[2];
    const float* proj_b  = (const float*)d_in[3];
    const float* conv_W0 = (const float*)d_in[4];
    const float* conv_b0 = (const float*)d_in[5];
    const float* conv_W1 = (const float*)d_in[6];
    const float* conv_b1 = (const float*)d_in[7];
    const float* conv_W2 = (const float*)d_in[8];
    const float* conv_b2 = (const float*)d_in[9];
    const float* out_W   = (const float*)d_in[10];
    const float* out_b   = (const float*)d_in[11];
    float* out = (float*)d_out;

    const int* src = eidx;
    const int* dst = eidx + N_EDGES;

    char* ws = (char*)d_ws;
    size_t off = 0;
    auto carve = [&](size_t bytes) {
        void* p = ws + off;
        off += (bytes + 255) & ~(size_t)255;
        return p;
    };
    int*    degi     = (int*)carve(N_NODES * sizeof(int));
    int*    row_ptr  = (int*)carve((N_NODES + 1) * sizeof(int));
    int*    cursor   = (int*)carve(N_NODES * sizeof(int));
    ushort* csr_src  = (ushort*)carve((size_t)N_TOT * sizeof(ushort));
    uint*   binned   = (uint*)carve((size_t)N_TOT * sizeof(uint));
    int*    bincur   = (int*)carve(N_BINS * sizeof(int));
    float*  dis      = (float*)carve(N_NODES * sizeof(float));
    int*    partials = (int*)carve(NB_SCAN * sizeof(int));
    int*    poff     = (int*)carve(NB_SCAN * sizeof(int));
    ushort* projPh = (ushort*)carve((size_t)IN_C * HID_C * sizeof(ushort));
    ushort* projPl = (ushort*)carve((size_t)IN_C * HID_C * sizeof(ushort));
    ushort* convPh[3], *convPl[3];
    for (int l = 0; l < 3; l++) {
        convPh[l] = (ushort*)carve((size_t)HID_C * HID_C * sizeof(ushort));
        convPl[l] = (ushort*)carve((size_t)HID_C * HID_C * sizeof(ushort));
    }
    ushort* outPh = (ushort*)carve((size_t)HID_C * OUT_C * sizeof(ushort));
    ushort* outPl = (ushort*)carve((size_t)HID_C * OUT_C * sizeof(ushort));
    uint*   hx = (uint*)carve((size_t)N_NODES * HID_C * sizeof(uint));       // packed hi/lo
    _Float16* g = (_Float16*)carve((size_t)N_NODES * HID_C * sizeof(_Float16));

    // Graph preprocessing
    init_deg_kernel<<<NB_SCAN, 256, 0, stream>>>(degi, bincur);
    count_deg_kernel<<<(N_EDGES + 255) / 256, 256, 0, stream>>>(dst, degi);
    deg_partial_kernel<<<NB_SCAN, 256, 0, stream>>>(degi, partials);
    scan_partials_kernel<<<1, 256, 0, stream>>>(partials, poff, row_ptr);
    scan_final_kernel<<<NB_SCAN, 256, 0, stream>>>(degi, poff, row_ptr, cursor, dis);
    bin_scatter_kernel<<<RB_GRID, RB_BLOCK, 0, stream>>>(
        src, dst, row_ptr, bincur, binned);
    csr_scatter_kernel<<<(N_TOT + 255) / 256, 256, 0, stream>>>(
        binned, cursor, csr_src);

    // Weight packing
    pack_w_kernel<<<(IN_C / 32) * (HID_C / 16), 64, 0, stream>>>(proj_W, projPh, projPl, IN_C, HID_C);
    pack_w_kernel<<<(HID_C / 32) * (HID_C / 16), 64, 0, stream>>>(conv_W0, convPh[0], convPl[0], HID_C, HID_C);
    pack_w_kernel<<<(HID_C / 32) * (HID_C / 16), 64, 0, stream>>>(conv_W1, convPh[1], convPl[1], HID_C, HID_C);
    pack_w_kernel<<<(HID_C / 32) * (HID_C / 16), 64, 0, stream>>>(conv_W2, convPh[2], convPl[2], HID_C, HID_C);
    pack_w_kernel<<<(HID_C / 32) * (OUT_C / 16), 64, 0, stream>>>(out_W, outPh, outPl, HID_C, OUT_C);

    const int grid_n128 = (N_NODES + 31) / 32;   // 1563 (N=128 kernels)
    const int grid_n64  = (N_NODES + 63) / 64;   // 782  (N=64 kernel)
    const int agg_grid  = (N_NODES + 3) / 4;     // 12500

    // Projection: hx = pack(x @ proj_W + proj_b)
    gemm_mfma_kernel<IN_C, HID_C, 1, true><<<grid_n128, 256, 0, stream>>>(
        x, nullptr, projPh, projPl, proj_b, nullptr, nullptr, hx, nullptr, N_NODES);

    // 3 GCN layers
    ushort* Wh_[3] = {convPh[0], convPh[1], convPh[2]};
    ushort* Wl_[3] = {convPl[0], convPl[1], convPl[2]};
    const float* bs_[3] = {conv_b0, conv_b1, conv_b2};
    for (int l = 0; l < 3; l++) {
        // g[node][128] = fp16(dis[node] * (h @ W)[node])
        gemm_mfma_kernel<HID_C, HID_C, 2, false><<<grid_n128, 256, 0, stream>>>(
            nullptr, hx, Wh_[l], Wl_[l], nullptr, dis, nullptr, nullptr, g, N_NODES);
        aggregate_kernel<<<agg_grid, 256, 0, stream>>>(
            g, row_ptr, csr_src, dis, bs_[l], hx);
    }

    // Output: out = h @ out_W + out_b (fp32)
    gemm_mfma_kernel<HID_C, OUT_C, 0, false><<<grid_n64, 256, 0, stream>>>(
        nullptr, hx, outPh, outPl, out_b, nullptr, out, nullptr, nullptr, N_NODES);
}